// Round 12
// baseline (195.409 us; speedup 1.0000x reference)
//
#include <hip/hip_runtime.h>
#include <hip/hip_bf16.h>
#include <math.h>

typedef unsigned short u16x8 __attribute__((ext_vector_type(8)));
typedef short s16x8 __attribute__((ext_vector_type(8)));
typedef float f32x4 __attribute__((ext_vector_type(4)));

#define BIN_TILE 4096
#define BCAP 8192  // per-bucket capacity in tmp; mean fill 4096, sigma ~64

__device__ __forceinline__ float bf2f(unsigned int u) {
    union { unsigned int i; float f; } x;
    x.i = u << 16;
    return x.f;
}
__device__ __forceinline__ unsigned short f2bf(float f) {
    __hip_bfloat16 h = __float2bfloat16(f);
    return *reinterpret_cast<unsigned short*>(&h);
}

// ---------------- setup: zero bcnt + W packs (MFMA B-frag order) + h2s sentinel ----------------
__global__ void setup_kernel(const float* __restrict__ W1, const float* __restrict__ W2,
                             unsigned short* __restrict__ w1p, unsigned short* __restrict__ w2p,
                             unsigned* __restrict__ h2z, int* __restrict__ bcnt) {
    int bid = blockIdx.x, tid = threadIdx.x;
    if (bid < 8) {  // w1 pack: 2048 threads
        int t = bid * 256 + tid;
        int lane = t & 63, fc = t >> 6;
        int ct = fc >> 2, kc = fc & 3;
        int n = ct * 16 + (lane & 15);
        int k0 = kc * 32 + (lane >> 4) * 8;
        u16x8 o;
#pragma unroll
        for (int j = 0; j < 8; j++) o[j] = f2bf(W1[(size_t)(k0 + j) * 128 + n]);
        ((u16x8*)w1p)[t] = o;
    } else if (bid < 11) {  // w2 pack: 768 threads
        int t = (bid - 8) * 256 + tid;
        int lane = t & 63, fc = t >> 6;
        int ct = fc >> 2, kc = fc & 3;
        int n = ct * 16 + (lane & 15);
        int k0 = kc * 32 + (lane >> 4) * 8;
        u16x8 o;
#pragma unroll
        for (int j = 0; j < 8; j++) o[j] = (n < 40) ? f2bf(W2[(size_t)(k0 + j) * 40 + n]) : (unsigned short)0;
        ((u16x8*)w2p)[t] = o;
    } else if (bid == 11) {  // zero h2s sentinel row N (128B)
        if (tid < 32) h2z[tid] = 0;
    } else {  // zero bcnt
        bcnt[tid] = 0;
        bcnt[tid + 256] = 0;
    }
}

// ---------------- single-pass bin: LDS hist -> reserve in fixed-cap bucket -> scatter ----------------
// tmp entry = row | (col&255)<<20, at tmp[(col>>8)*BCAP + slot]
__global__ void bin_kernel(const int* __restrict__ row, const int* __restrict__ col,
                           int* __restrict__ bcnt, unsigned* __restrict__ tmp, int E, int NB) {
    __shared__ unsigned hist[512];
    int tid = threadIdx.x;
    int base = blockIdx.x * BIN_TILE;
    for (int i = tid; i < NB; i += 256) hist[i] = 0;
    __syncthreads();
#pragma unroll
    for (int i = 0; i < BIN_TILE / 256; i++) {
        int e = base + tid + i * 256;
        if (e < E) atomicAdd(&hist[col[e] >> 8], 1u);
    }
    __syncthreads();
    for (int i = tid; i < NB; i += 256) {
        unsigned h = hist[i];
        hist[i] = h ? (unsigned)atomicAdd(&bcnt[i], (int)h) : 0u;  // local cursor base
    }
    __syncthreads();
#pragma unroll
    for (int i = 0; i < BIN_TILE / 256; i++) {
        int e = base + tid + i * 256;
        if (e < E) {
            int c = col[e], r = row[e];
            unsigned p = atomicAdd(&hist[c >> 8], 1u);
            tmp[(size_t)(c >> 8) * BCAP + p] = (unsigned)r | ((unsigned)(c & 255) << 20);
        }
    }
}

// ---------------- per bucket: prefix (inline reduce) + cnt/offs/dis + fine scatter ----------------
__global__ void bucket_kernel(const unsigned* __restrict__ tmp, const int* __restrict__ bcnt,
                              int* __restrict__ cnt, int* __restrict__ offs,
                              float* __restrict__ dis, int* __restrict__ csr, int N, int NB) {
    __shared__ int cntS[256], curS[256], sA[256], sB[256];
    int b = blockIdx.x;
    int tid = threadIdx.x;
    size_t tbase = (size_t)b * BCAP;

    // start = sum_{i<b} bcnt[i]  (block reduce; bcnt is tiny and L2-hot)
    cntS[tid] = 0;
    int partial = 0;
    if (tid < b) partial += bcnt[tid];
    if (tid + 256 < b) partial += bcnt[tid + 256];
    sA[tid] = partial;
    __syncthreads();
    for (int s = 128; s > 0; s >>= 1) {
        if (tid < s) sA[tid] += sA[tid + s];
        __syncthreads();
    }
    int start = sA[0];
    int ecnt = bcnt[b];

    // per-node degree histogram (LDS)
    for (int i = tid; i < ecnt; i += 256)
        atomicAdd(&cntS[(tmp[tbase + i] >> 20) & 255], 1);
    __syncthreads();
    int myCnt = cntS[tid];
    sA[tid] = myCnt;
    __syncthreads();
    int* src = sA;
    int* dst = sB;
    for (int off = 1; off < 256; off <<= 1) {
        dst[tid] = src[tid] + ((tid >= off) ? src[tid - off] : 0);
        __syncthreads();
        int* t = src; src = dst; dst = t;
    }
    int excl = src[tid] - myCnt;
    int node = (b << 8) + tid;
    if (node < N) {
        cnt[node] = myCnt;
        offs[node] = start + excl;
        dis[node] = rsqrtf((float)myCnt + 1.0f);
    }
    curS[tid] = excl;
    __syncthreads();
    for (int i = tid; i < ecnt; i += 256) {
        unsigned u = tmp[tbase + i];
        int cl = (u >> 20) & 255;
        int p = atomicAdd(&curS[cl], 1);
        csr[start + p] = (int)(u & 0xFFFFFu);
    }
}

// ---------------- xbs[i] = bf16(dis[i]*x[i]); sentinel row N = 0 ----------------
__global__ void scale_cvt_kernel(const float* __restrict__ x, const float* __restrict__ dis,
                                 unsigned short* __restrict__ xbs, int N) {
    long idx = (long)blockIdx.x * blockDim.x + threadIdx.x;  // one u16x8 chunk
    long total8 = (long)(N + 1) * 16;
    if (idx >= total8) return;
    int i = (int)(idx >> 4);
    u16x8 o;
    if (i >= N) {
#pragma unroll
        for (int k = 0; k < 8; k++) o[k] = 0;
    } else {
        float d = dis[i];
        float4 a = ((const float4*)x)[2 * idx];
        float4 b = ((const float4*)x)[2 * idx + 1];
        o[0] = f2bf(d * a.x); o[1] = f2bf(d * a.y); o[2] = f2bf(d * a.z); o[3] = f2bf(d * a.w);
        o[4] = f2bf(d * b.x); o[5] = f2bf(d * b.y); o[6] = f2bf(d * b.z); o[7] = f2bf(d * b.w);
    }
    ((u16x8*)xbs)[idx] = o;
}

// ---------------- fused gather1 + MLP ----------------
// Block = 64 nodes, 4 waves. Wave wv gathers nodes [n0+wv*16, +16) sequentially
// into the LDS tile (bf16), then MFMA: a1 = relu(xt@W1+b1) (in-place LDS),
// h2s = dis .* (a1@W2). xa never touches HBM.
__global__ __launch_bounds__(256, 6) void g1mlp_kernel(const unsigned short* __restrict__ xbs,
                                                       const int* __restrict__ offs,
                                                       const int* __restrict__ cnt,
                                                       const int* __restrict__ csr,
                                                       const float* __restrict__ dis,
                                                       const unsigned short* __restrict__ w1p,
                                                       const unsigned short* __restrict__ w2p,
                                                       const float* __restrict__ b1,
                                                       unsigned short* __restrict__ h2s, int N) {
    __shared__ unsigned short xt[64][136];
    int tid = threadIdx.x;
    int wv = tid >> 6;
    int l = tid & 63;
    int g = l >> 4, c = l & 15;
    int n0 = blockIdx.x * 64;
    const u16x8* XB = (const u16x8*)xbs;

    // ---- gather phase: 16 nodes per wave, 16 edges in flight each
    for (int i = 0; i < 16; i++) {
        int node = n0 + wv * 16 + i;
        int off = 0, dg = 0;
        if (node < N) { off = offs[node]; dg = cnt[node]; }
        float acc[8] = {};
        int s0 = (g      < dg) ? csr[off + g]      : N;
        int s1 = (g + 4  < dg) ? csr[off + g + 4]  : N;
        int s2 = (g + 8  < dg) ? csr[off + g + 8]  : N;
        int s3 = (g + 12 < dg) ? csr[off + g + 12] : N;
        for (int j = 0; j < dg; j += 16) {
            int jb = j + 16;
            int t0 = (jb + g      < dg) ? csr[off + jb + g]      : N;
            int t1 = (jb + g + 4  < dg) ? csr[off + jb + g + 4]  : N;
            int t2 = (jb + g + 8  < dg) ? csr[off + jb + g + 8]  : N;
            int t3 = (jb + g + 12 < dg) ? csr[off + jb + g + 12] : N;
            u16x8 v0 = XB[(size_t)s0 * 16 + c];
            u16x8 v1 = XB[(size_t)s1 * 16 + c];
            u16x8 v2 = XB[(size_t)s2 * 16 + c];
            u16x8 v3 = XB[(size_t)s3 * 16 + c];
#pragma unroll
            for (int k = 0; k < 8; k++)
                acc[k] += (bf2f(v0[k]) + bf2f(v1[k])) + (bf2f(v2[k]) + bf2f(v3[k]));
            s0 = t0; s1 = t1; s2 = t2; s3 = t3;
        }
#pragma unroll
        for (int k = 0; k < 8; k++) {
            acc[k] += __shfl_xor(acc[k], 16);
            acc[k] += __shfl_xor(acc[k], 32);
        }
        int nodec = (node < N) ? node : N;   // sentinel row N is zero
        float dc = (node < N) ? dis[node] : 0.f;
        u16x8 xv = XB[(size_t)nodec * 16 + c];
        if (l < 16) {
            u16x8 o;
#pragma unroll
            for (int k = 0; k < 8; k++) o[k] = f2bf(dc * (acc[k] + bf2f(xv[k])));
            *(u16x8*)&xt[wv * 16 + i][c * 8] = o;
        }
    }
    __syncthreads();

    // ---- MFMA phase 1: acc = xt @ W1 (per-wave 16x128 tile)
    int row16 = l & 15, kg = l >> 4;
    int rbase = n0 + wv * 16;
    f32x4 acc1[8];
#pragma unroll
    for (int ct = 0; ct < 8; ct++) acc1[ct] = (f32x4)0.f;
#pragma unroll
    for (int kc = 0; kc < 4; kc++) {
        s16x8 af = *(const s16x8*)&xt[wv * 16 + row16][kc * 32 + kg * 8];
#pragma unroll
        for (int ct = 0; ct < 8; ct++) {
            s16x8 bf = *(const s16x8*)(w1p + (size_t)((ct * 4 + kc) * 64 + l) * 8);
            acc1[ct] = __builtin_amdgcn_mfma_f32_16x16x32_bf16(af, bf, acc1[ct], 0, 0, 0);
        }
    }
    // bias + relu -> back into own wave's LDS rows
#pragma unroll
    for (int ct = 0; ct < 8; ct++) {
        float bb = b1[ct * 16 + row16];
#pragma unroll
        for (int v = 0; v < 4; v++)
            xt[wv * 16 + kg * 4 + v][ct * 16 + row16] = f2bf(fmaxf(acc1[ct][v] + bb, 0.f));
    }

    // ---- MFMA phase 2: h2s = dis .* (a1 @ W2)
    f32x4 acc2[3];
#pragma unroll
    for (int ct = 0; ct < 3; ct++) acc2[ct] = (f32x4)0.f;
#pragma unroll
    for (int kc = 0; kc < 4; kc++) {
        s16x8 af = *(const s16x8*)&xt[wv * 16 + row16][kc * 32 + kg * 8];
#pragma unroll
        for (int ct = 0; ct < 3; ct++) {
            s16x8 bf = *(const s16x8*)(w2p + (size_t)((ct * 4 + kc) * 64 + l) * 8);
            acc2[ct] = __builtin_amdgcn_mfma_f32_16x16x32_bf16(af, bf, acc2[ct], 0, 0, 0);
        }
    }
#pragma unroll
    for (int v = 0; v < 4; v++) {
        int rr = rbase + kg * 4 + v;
        if (rr < N) {
            float d = dis[rr];
#pragma unroll
            for (int ct = 0; ct < 3; ct++)
                h2s[(size_t)rr * 64 + ct * 16 + row16] = f2bf(d * acc2[ct][v]);
        }
    }
}

// ---------------- gather2: log_softmax(dc*(sum_s h2s[s] + h2s[node]) + b2) ----------------
// 6 groups x 10 lanes (ushort4 = 4 cols/lane), 4 slots -> 24 edges in flight
__global__ void gather2_kernel(const unsigned short* __restrict__ h2s, const int* __restrict__ offs,
                               const int* __restrict__ cnt, const int* __restrict__ csr,
                               const float* __restrict__ dis, const float* __restrict__ b2,
                               float* __restrict__ out, int N) {
    int node = blockIdx.x * 4 + (threadIdx.x >> 6);
    int lane = threadIdx.x & 63;
    if (node >= N) return;
    int off = offs[node], dg = cnt[node];
    int c = lane % 10;            // ushort4 index within row (cols 4c..4c+3)
    int g = lane / 10;
    if (g > 5) g = 5;             // lanes 60-63 duplicate group 5 (harmless)
    const ushort4* H4 = (const ushort4*)h2s;  // 16 ushort4 per 64-col row
    float a0 = 0.f, a1 = 0.f, a2 = 0.f, a3 = 0.f;
    int s0 = (g      < dg) ? csr[off + g]      : N;
    int s1 = (g + 6  < dg) ? csr[off + g + 6]  : N;
    int s2 = (g + 12 < dg) ? csr[off + g + 12] : N;
    int s3 = (g + 18 < dg) ? csr[off + g + 18] : N;
    for (int j = 0; j < dg; j += 24) {
        int jb = j + 24;
        int t0 = (jb + g      < dg) ? csr[off + jb + g]      : N;
        int t1 = (jb + g + 6  < dg) ? csr[off + jb + g + 6]  : N;
        int t2 = (jb + g + 12 < dg) ? csr[off + jb + g + 12] : N;
        int t3 = (jb + g + 18 < dg) ? csr[off + jb + g + 18] : N;
        ushort4 u0 = H4[(size_t)s0 * 16 + c];
        ushort4 u1 = H4[(size_t)s1 * 16 + c];
        ushort4 u2 = H4[(size_t)s2 * 16 + c];
        ushort4 u3 = H4[(size_t)s3 * 16 + c];
        a0 += (bf2f(u0.x) + bf2f(u1.x)) + (bf2f(u2.x) + bf2f(u3.x));
        a1 += (bf2f(u0.y) + bf2f(u1.y)) + (bf2f(u2.y) + bf2f(u3.y));
        a2 += (bf2f(u0.z) + bf2f(u1.z)) + (bf2f(u2.z) + bf2f(u3.z));
        a3 += (bf2f(u0.w) + bf2f(u1.w)) + (bf2f(u2.w) + bf2f(u3.w));
        s0 = t0; s1 = t1; s2 = t2; s3 = t3;
    }
    // fold 6 groups -> lanes 0-9.  step1: lanes 0-29 += lanes 30-59 (g+3)
    float t;
    t = __shfl(a0, lane + 30); a0 += t;
    t = __shfl(a1, lane + 30); a1 += t;
    t = __shfl(a2, lane + 30); a2 += t;
    t = __shfl(a3, lane + 30); a3 += t;
    // step2: lanes 0-9 += lanes 10-19 and 20-29
    float p, q;
    p = __shfl(a0, lane + 10); q = __shfl(a0, lane + 20); a0 += p + q;
    p = __shfl(a1, lane + 10); q = __shfl(a1, lane + 20); a1 += p + q;
    p = __shfl(a2, lane + 10); q = __shfl(a2, lane + 20); a2 += p + q;
    p = __shfl(a3, lane + 10); q = __shfl(a3, lane + 20); a3 += p + q;

    bool act = lane < 10;
    float dc = dis[node];
    ushort4 uv = H4[(size_t)node * 16 + c];
    float4 bb = ((const float4*)b2)[c];  // cols 4c..4c+3
    float v0 = -INFINITY, v1 = -INFINITY, v2 = -INFINITY, v3 = -INFINITY;
    if (act) {
        v0 = dc * (a0 + bf2f(uv.x)) + bb.x;
        v1 = dc * (a1 + bf2f(uv.y)) + bb.y;
        v2 = dc * (a2 + bf2f(uv.z)) + bb.z;
        v3 = dc * (a3 + bf2f(uv.w)) + bb.w;
    }
    float m = fmaxf(fmaxf(v0, v1), fmaxf(v2, v3));
#pragma unroll
    for (int o = 32; o > 0; o >>= 1) m = fmaxf(m, __shfl_xor(m, o));
    float ex = act ? (__expf(v0 - m) + __expf(v1 - m) + __expf(v2 - m) + __expf(v3 - m)) : 0.f;
#pragma unroll
    for (int o = 32; o > 0; o >>= 1) ex += __shfl_xor(ex, o);
    float ls = __logf(ex);  // values live only on lanes 0-9 -> single-counted
    if (act) {
        float4 o4 = make_float4(v0 - m - ls, v1 - m - ls, v2 - m - ls, v3 - m - ls);
        ((float4*)(out + (size_t)node * 40))[c] = o4;
    }
}

extern "C" void kernel_launch(void* const* d_in, const int* in_sizes, int n_in,
                              void* d_out, int out_size, void* d_ws, size_t ws_size,
                              hipStream_t stream) {
    const float* x  = (const float*)d_in[0];
    const int*   ei = (const int*)d_in[1];
    const float* W1 = (const float*)d_in[2];
    const float* b1 = (const float*)d_in[3];
    const float* W2 = (const float*)d_in[4];
    const float* b2 = (const float*)d_in[5];
    float* out = (float*)d_out;

    const int N = in_sizes[0] / 128;
    const int E = in_sizes[1] / 2;
    const int* row = ei;
    const int* col = ei + E;

    const int Npad = (N + 511) & ~511;
    const int Epad = (E + 511) & ~511;
    const int NB = (N + 255) >> 8;  // coarse buckets (col>>8); <=512

    int* cnt      = (int*)d_ws;           // Npad
    int* offs     = cnt + Npad;           // Npad
    int* bcnt     = offs + Npad;          // 512 (pad 1024)
    int* csr      = bcnt + 1024;          // Epad
    unsigned* tmp = (unsigned*)(csr + Epad);              // NB*BCAP (<= 512*8192 = 16MB)
    float* dis    = (float*)(tmp + (size_t)NB * BCAP);    // Npad
    unsigned short* w1p = (unsigned short*)(dis + Npad);  // 16384 ush
    unsigned short* w2p = w1p + 16384;                    // 6144 ush (pad 8192)
    unsigned short* xbs = w2p + 8192;                     // (N+1)*128 bf16
    unsigned short* h2s = xbs + (size_t)(N + 1) * 128;    // (N+1)*64 bf16

    // 1) setup (bcnt zero + weight packs + h2s sentinel) -> CSR build
    setup_kernel<<<13, 256, 0, stream>>>(W1, W2, w1p, w2p,
                                         (unsigned*)(h2s + (size_t)N * 64), bcnt);
    bin_kernel<<<(E + BIN_TILE - 1) / BIN_TILE, 256, 0, stream>>>(row, col, bcnt, tmp, E, NB);
    bucket_kernel<<<NB, 256, 0, stream>>>(tmp, bcnt, cnt, offs, dis, csr, N, NB);

    // 2) pre-scaled bf16 features
    {
        long total8 = (long)(N + 1) * 16;
        scale_cvt_kernel<<<(int)((total8 + 255) / 256), 256, 0, stream>>>(x, dis, xbs, N);
    }

    // 3) fused: gather1 (LDS) + h2s = dis .* (relu(xa@W1+b1) @ W2)
    g1mlp_kernel<<<(N + 63) / 64, 256, 0, stream>>>(xbs, offs, cnt, csr, dis,
                                                    w1p, w2p, b1, h2s, N);

    // 4) out = log_softmax(dc*(sum + self) + b2)
    gather2_kernel<<<(N + 3) / 4, 256, 0, stream>>>(h2s, offs, cnt, csr, dis, b2, out, N);
}

// Round 13
// 176.756 us; speedup vs baseline: 1.1055x; 1.1055x over previous
//
#include <hip/hip_runtime.h>
#include <hip/hip_bf16.h>
#include <math.h>

typedef unsigned short u16x8 __attribute__((ext_vector_type(8)));
typedef short s16x8 __attribute__((ext_vector_type(8)));
typedef float f32x4 __attribute__((ext_vector_type(4)));

#define BIN_TILE 4096
#define BCAP 8192  // per-bucket capacity in tmp; mean fill 4096, sigma ~64

__device__ __forceinline__ float bf2f(unsigned int u) {
    union { unsigned int i; float f; } x;
    x.i = u << 16;
    return x.f;
}
__device__ __forceinline__ unsigned short f2bf(float f) {
    __hip_bfloat16 h = __float2bfloat16(f);
    return *reinterpret_cast<unsigned short*>(&h);
}

// ---------------- setup: zero bcnt + W packs (MFMA B-frag order) + h2s sentinel ----------------
__global__ void setup_kernel(const float* __restrict__ W1, const float* __restrict__ W2,
                             unsigned short* __restrict__ w1p, unsigned short* __restrict__ w2p,
                             unsigned* __restrict__ h2z, int* __restrict__ bcnt) {
    int bid = blockIdx.x, tid = threadIdx.x;
    if (bid < 8) {  // w1 pack: 2048 threads
        int t = bid * 256 + tid;
        int lane = t & 63, fc = t >> 6;
        int ct = fc >> 2, kc = fc & 3;
        int n = ct * 16 + (lane & 15);
        int k0 = kc * 32 + (lane >> 4) * 8;
        u16x8 o;
#pragma unroll
        for (int j = 0; j < 8; j++) o[j] = f2bf(W1[(size_t)(k0 + j) * 128 + n]);
        ((u16x8*)w1p)[t] = o;
    } else if (bid < 11) {  // w2 pack: 768 threads
        int t = (bid - 8) * 256 + tid;
        int lane = t & 63, fc = t >> 6;
        int ct = fc >> 2, kc = fc & 3;
        int n = ct * 16 + (lane & 15);
        int k0 = kc * 32 + (lane >> 4) * 8;
        u16x8 o;
#pragma unroll
        for (int j = 0; j < 8; j++) o[j] = (n < 40) ? f2bf(W2[(size_t)(k0 + j) * 40 + n]) : (unsigned short)0;
        ((u16x8*)w2p)[t] = o;
    } else if (bid == 11) {  // zero h2s sentinel row N (128B)
        if (tid < 32) h2z[tid] = 0;
    } else {  // zero bcnt
        bcnt[tid] = 0;
        bcnt[tid + 256] = 0;
    }
}

// ---------------- single-pass bin: LDS hist -> reserve in fixed-cap bucket -> scatter ----------------
// tmp entry = row | (col&255)<<20, at tmp[(col>>8)*BCAP + slot]
__global__ void bin_kernel(const int* __restrict__ row, const int* __restrict__ col,
                           int* __restrict__ bcnt, unsigned* __restrict__ tmp, int E, int NB) {
    __shared__ unsigned hist[512];
    int tid = threadIdx.x;
    int base = blockIdx.x * BIN_TILE;
    for (int i = tid; i < NB; i += 256) hist[i] = 0;
    __syncthreads();
#pragma unroll
    for (int i = 0; i < BIN_TILE / 256; i++) {
        int e = base + tid + i * 256;
        if (e < E) atomicAdd(&hist[col[e] >> 8], 1u);
    }
    __syncthreads();
    for (int i = tid; i < NB; i += 256) {
        unsigned h = hist[i];
        hist[i] = h ? (unsigned)atomicAdd(&bcnt[i], (int)h) : 0u;  // local cursor base
    }
    __syncthreads();
#pragma unroll
    for (int i = 0; i < BIN_TILE / 256; i++) {
        int e = base + tid + i * 256;
        if (e < E) {
            int c = col[e], r = row[e];
            unsigned p = atomicAdd(&hist[c >> 8], 1u);
            tmp[(size_t)(c >> 8) * BCAP + p] = (unsigned)r | ((unsigned)(c & 255) << 20);
        }
    }
}

// ---------------- per bucket: prefix (inline reduce) + cnt/offs/dis + fine scatter ----------------
__global__ void bucket_kernel(const unsigned* __restrict__ tmp, const int* __restrict__ bcnt,
                              int* __restrict__ cnt, int* __restrict__ offs,
                              float* __restrict__ dis, int* __restrict__ csr, int N, int NB) {
    __shared__ int cntS[256], curS[256], sA[256], sB[256];
    int b = blockIdx.x;
    int tid = threadIdx.x;
    size_t tbase = (size_t)b * BCAP;

    // start = sum_{i<b} bcnt[i]  (block reduce; bcnt is tiny and L2-hot)
    cntS[tid] = 0;
    int partial = 0;
    if (tid < b) partial += bcnt[tid];
    if (tid + 256 < b) partial += bcnt[tid + 256];
    sA[tid] = partial;
    __syncthreads();
    for (int s = 128; s > 0; s >>= 1) {
        if (tid < s) sA[tid] += sA[tid + s];
        __syncthreads();
    }
    int start = sA[0];
    int ecnt = bcnt[b];

    // per-node degree histogram (LDS)
    for (int i = tid; i < ecnt; i += 256)
        atomicAdd(&cntS[(tmp[tbase + i] >> 20) & 255], 1);
    __syncthreads();
    int myCnt = cntS[tid];
    sA[tid] = myCnt;
    __syncthreads();
    int* src = sA;
    int* dst = sB;
    for (int off = 1; off < 256; off <<= 1) {
        dst[tid] = src[tid] + ((tid >= off) ? src[tid - off] : 0);
        __syncthreads();
        int* t = src; src = dst; dst = t;
    }
    int excl = src[tid] - myCnt;
    int node = (b << 8) + tid;
    if (node < N) {
        cnt[node] = myCnt;
        offs[node] = start + excl;
        dis[node] = rsqrtf((float)myCnt + 1.0f);
    }
    curS[tid] = excl;
    __syncthreads();
    for (int i = tid; i < ecnt; i += 256) {
        unsigned u = tmp[tbase + i];
        int cl = (u >> 20) & 255;
        int p = atomicAdd(&curS[cl], 1);
        csr[start + p] = (int)(u & 0xFFFFFu);
    }
}

// ---------------- xbs[i] = bf16(dis[i]*x[i]); sentinel row N = 0 ----------------
__global__ void scale_cvt_kernel(const float* __restrict__ x, const float* __restrict__ dis,
                                 unsigned short* __restrict__ xbs, int N) {
    long idx = (long)blockIdx.x * blockDim.x + threadIdx.x;  // one u16x8 chunk
    long total8 = (long)(N + 1) * 16;
    if (idx >= total8) return;
    int i = (int)(idx >> 4);
    u16x8 o;
    if (i >= N) {
#pragma unroll
        for (int k = 0; k < 8; k++) o[k] = 0;
    } else {
        float d = dis[i];
        float4 a = ((const float4*)x)[2 * idx];
        float4 b = ((const float4*)x)[2 * idx + 1];
        o[0] = f2bf(d * a.x); o[1] = f2bf(d * a.y); o[2] = f2bf(d * a.z); o[3] = f2bf(d * a.w);
        o[4] = f2bf(d * b.x); o[5] = f2bf(d * b.y); o[6] = f2bf(d * b.z); o[7] = f2bf(d * b.w);
    }
    ((u16x8*)xbs)[idx] = o;
}

// ---------------- gather1: xa[c] = dc * ( sum_s xbs[s] + xbs[c] ), 16 edges in flight ----------------
__global__ void gather1_kernel(const unsigned short* __restrict__ xbs, const int* __restrict__ offs,
                               const int* __restrict__ cnt, const int* __restrict__ csr,
                               const float* __restrict__ dis, unsigned short* __restrict__ xa, int N) {
    int node = blockIdx.x * 4 + (threadIdx.x >> 6);
    int lane = threadIdx.x & 63;
    if (node >= N) return;
    int off = offs[node], dg = cnt[node];
    int g = lane >> 4, c = lane & 15;
    const u16x8* XB = (const u16x8*)xbs;
    float acc[8] = {};
    int s0 = (g      < dg) ? csr[off + g]      : N;
    int s1 = (g + 4  < dg) ? csr[off + g + 4]  : N;
    int s2 = (g + 8  < dg) ? csr[off + g + 8]  : N;
    int s3 = (g + 12 < dg) ? csr[off + g + 12] : N;
    for (int j = 0; j < dg; j += 16) {
        int jb = j + 16;
        int t0 = (jb + g      < dg) ? csr[off + jb + g]      : N;
        int t1 = (jb + g + 4  < dg) ? csr[off + jb + g + 4]  : N;
        int t2 = (jb + g + 8  < dg) ? csr[off + jb + g + 8]  : N;
        int t3 = (jb + g + 12 < dg) ? csr[off + jb + g + 12] : N;
        u16x8 v0 = XB[(size_t)s0 * 16 + c];
        u16x8 v1 = XB[(size_t)s1 * 16 + c];
        u16x8 v2 = XB[(size_t)s2 * 16 + c];
        u16x8 v3 = XB[(size_t)s3 * 16 + c];
#pragma unroll
        for (int k = 0; k < 8; k++)
            acc[k] += (bf2f(v0[k]) + bf2f(v1[k])) + (bf2f(v2[k]) + bf2f(v3[k]));
        s0 = t0; s1 = t1; s2 = t2; s3 = t3;
    }
#pragma unroll
    for (int k = 0; k < 8; k++) {
        acc[k] += __shfl_xor(acc[k], 16);
        acc[k] += __shfl_xor(acc[k], 32);
    }
    float dc = dis[node];
    u16x8 xv = XB[(size_t)node * 16 + c];
    if (lane < 16) {
        u16x8 o;
#pragma unroll
        for (int k = 0; k < 8; k++) o[k] = f2bf(dc * (acc[k] + bf2f(xv[k])));
        ((u16x8*)xa)[(size_t)node * 16 + c] = o;
    }
}

// ---------------- fused MLP (MFMA): h2s = dis .* relu(xa@W1+b1) @ W2 ----------------
__global__ __launch_bounds__(256) void mlp_kernel(const unsigned short* __restrict__ xa,
                                                  const unsigned short* __restrict__ w1p,
                                                  const unsigned short* __restrict__ w2p,
                                                  const float* __restrict__ b1,
                                                  const float* __restrict__ dis,
                                                  unsigned short* __restrict__ h2s, int N) {
    __shared__ unsigned short a1s[64][136];
    int wv = threadIdx.x >> 6;
    int l = threadIdx.x & 63;
    int row16 = l & 15, kg = l >> 4;
    int n0 = blockIdx.x * 64;
    int rbase = n0 + wv * 16;

    f32x4 acc[8];
#pragma unroll
    for (int ct = 0; ct < 8; ct++) acc[ct] = (f32x4)0.f;
    int r = rbase + row16;
    int rc = (r < N) ? r : (N - 1);
#pragma unroll
    for (int kc = 0; kc < 4; kc++) {
        s16x8 af = *(const s16x8*)(xa + (size_t)rc * 128 + kc * 32 + kg * 8);
#pragma unroll
        for (int ct = 0; ct < 8; ct++) {
            s16x8 bf = *(const s16x8*)(w1p + (size_t)((ct * 4 + kc) * 64 + l) * 8);
            acc[ct] = __builtin_amdgcn_mfma_f32_16x16x32_bf16(af, bf, acc[ct], 0, 0, 0);
        }
    }
#pragma unroll
    for (int ct = 0; ct < 8; ct++) {
        float bb = b1[ct * 16 + row16];
#pragma unroll
        for (int v = 0; v < 4; v++)
            a1s[wv * 16 + kg * 4 + v][ct * 16 + row16] = f2bf(fmaxf(acc[ct][v] + bb, 0.f));
    }
    __syncthreads();

    f32x4 acc2[3];
#pragma unroll
    for (int ct = 0; ct < 3; ct++) acc2[ct] = (f32x4)0.f;
#pragma unroll
    for (int kc = 0; kc < 4; kc++) {
        s16x8 af = *(const s16x8*)&a1s[wv * 16 + row16][kc * 32 + kg * 8];
#pragma unroll
        for (int ct = 0; ct < 3; ct++) {
            s16x8 bf = *(const s16x8*)(w2p + (size_t)((ct * 4 + kc) * 64 + l) * 8);
            acc2[ct] = __builtin_amdgcn_mfma_f32_16x16x32_bf16(af, bf, acc2[ct], 0, 0, 0);
        }
    }
#pragma unroll
    for (int v = 0; v < 4; v++) {
        int rr = rbase + kg * 4 + v;
        if (rr < N) {
            float d = dis[rr];
#pragma unroll
            for (int ct = 0; ct < 3; ct++)
                h2s[(size_t)rr * 64 + ct * 16 + row16] = f2bf(d * acc2[ct][v]);
        }
    }
}

// ---------------- gather2: log_softmax(dc*(sum_s h2s[s] + h2s[node]) + b2) ----------------
// 6 groups x 10 lanes (ushort4 = 4 cols/lane), 4 slots -> 24 edges in flight
__global__ void gather2_kernel(const unsigned short* __restrict__ h2s, const int* __restrict__ offs,
                               const int* __restrict__ cnt, const int* __restrict__ csr,
                               const float* __restrict__ dis, const float* __restrict__ b2,
                               float* __restrict__ out, int N) {
    int node = blockIdx.x * 4 + (threadIdx.x >> 6);
    int lane = threadIdx.x & 63;
    if (node >= N) return;
    int off = offs[node], dg = cnt[node];
    int c = lane % 10;            // ushort4 index within row (cols 4c..4c+3)
    int g = lane / 10;
    if (g > 5) g = 5;             // lanes 60-63 duplicate group 5 (harmless)
    const ushort4* H4 = (const ushort4*)h2s;  // 16 ushort4 per 64-col row
    float a0 = 0.f, a1 = 0.f, a2 = 0.f, a3 = 0.f;
    int s0 = (g      < dg) ? csr[off + g]      : N;
    int s1 = (g + 6  < dg) ? csr[off + g + 6]  : N;
    int s2 = (g + 12 < dg) ? csr[off + g + 12] : N;
    int s3 = (g + 18 < dg) ? csr[off + g + 18] : N;
    for (int j = 0; j < dg; j += 24) {
        int jb = j + 24;
        int t0 = (jb + g      < dg) ? csr[off + jb + g]      : N;
        int t1 = (jb + g + 6  < dg) ? csr[off + jb + g + 6]  : N;
        int t2 = (jb + g + 12 < dg) ? csr[off + jb + g + 12] : N;
        int t3 = (jb + g + 18 < dg) ? csr[off + jb + g + 18] : N;
        ushort4 u0 = H4[(size_t)s0 * 16 + c];
        ushort4 u1 = H4[(size_t)s1 * 16 + c];
        ushort4 u2 = H4[(size_t)s2 * 16 + c];
        ushort4 u3 = H4[(size_t)s3 * 16 + c];
        a0 += (bf2f(u0.x) + bf2f(u1.x)) + (bf2f(u2.x) + bf2f(u3.x));
        a1 += (bf2f(u0.y) + bf2f(u1.y)) + (bf2f(u2.y) + bf2f(u3.y));
        a2 += (bf2f(u0.z) + bf2f(u1.z)) + (bf2f(u2.z) + bf2f(u3.z));
        a3 += (bf2f(u0.w) + bf2f(u1.w)) + (bf2f(u2.w) + bf2f(u3.w));
        s0 = t0; s1 = t1; s2 = t2; s3 = t3;
    }
    // fold 6 groups -> lanes 0-9.  step1: lanes 0-29 += lanes 30-59 (g+3)
    float t;
    t = __shfl(a0, lane + 30); a0 += t;
    t = __shfl(a1, lane + 30); a1 += t;
    t = __shfl(a2, lane + 30); a2 += t;
    t = __shfl(a3, lane + 30); a3 += t;
    // step2: lanes 0-9 += lanes 10-19 and 20-29
    float p, q;
    p = __shfl(a0, lane + 10); q = __shfl(a0, lane + 20); a0 += p + q;
    p = __shfl(a1, lane + 10); q = __shfl(a1, lane + 20); a1 += p + q;
    p = __shfl(a2, lane + 10); q = __shfl(a2, lane + 20); a2 += p + q;
    p = __shfl(a3, lane + 10); q = __shfl(a3, lane + 20); a3 += p + q;

    bool act = lane < 10;
    float dc = dis[node];
    ushort4 uv = H4[(size_t)node * 16 + c];
    float4 bb = ((const float4*)b2)[c];  // cols 4c..4c+3
    float v0 = -INFINITY, v1 = -INFINITY, v2 = -INFINITY, v3 = -INFINITY;
    if (act) {
        v0 = dc * (a0 + bf2f(uv.x)) + bb.x;
        v1 = dc * (a1 + bf2f(uv.y)) + bb.y;
        v2 = dc * (a2 + bf2f(uv.z)) + bb.z;
        v3 = dc * (a3 + bf2f(uv.w)) + bb.w;
    }
    float m = fmaxf(fmaxf(v0, v1), fmaxf(v2, v3));
#pragma unroll
    for (int o = 32; o > 0; o >>= 1) m = fmaxf(m, __shfl_xor(m, o));
    float ex = act ? (__expf(v0 - m) + __expf(v1 - m) + __expf(v2 - m) + __expf(v3 - m)) : 0.f;
#pragma unroll
    for (int o = 32; o > 0; o >>= 1) ex += __shfl_xor(ex, o);
    float ls = __logf(ex);  // values live only on lanes 0-9 -> single-counted
    if (act) {
        float4 o4 = make_float4(v0 - m - ls, v1 - m - ls, v2 - m - ls, v3 - m - ls);
        ((float4*)(out + (size_t)node * 40))[c] = o4;
    }
}

extern "C" void kernel_launch(void* const* d_in, const int* in_sizes, int n_in,
                              void* d_out, int out_size, void* d_ws, size_t ws_size,
                              hipStream_t stream) {
    const float* x  = (const float*)d_in[0];
    const int*   ei = (const int*)d_in[1];
    const float* W1 = (const float*)d_in[2];
    const float* b1 = (const float*)d_in[3];
    const float* W2 = (const float*)d_in[4];
    const float* b2 = (const float*)d_in[5];
    float* out = (float*)d_out;

    const int N = in_sizes[0] / 128;
    const int E = in_sizes[1] / 2;
    const int* row = ei;
    const int* col = ei + E;

    const int Npad = (N + 511) & ~511;
    const int Epad = (E + 511) & ~511;
    const int NB = (N + 255) >> 8;  // coarse buckets (col>>8); <=512

    int* cnt      = (int*)d_ws;           // Npad
    int* offs     = cnt + Npad;           // Npad
    int* bcnt     = offs + Npad;          // 512 (pad 1024)
    int* csr      = bcnt + 1024;          // Epad
    unsigned* tmp = (unsigned*)(csr + Epad);              // NB*BCAP (<= 512*8192 = 16MB)
    float* dis    = (float*)(tmp + (size_t)NB * BCAP);    // Npad
    unsigned short* w1p = (unsigned short*)(dis + Npad);  // 16384 ush
    unsigned short* w2p = w1p + 16384;                    // 6144 ush (pad 8192)
    unsigned short* xbs = w2p + 8192;                     // (N+1)*128 bf16
    unsigned short* xa  = xbs + (size_t)(N + 1) * 128;    // N*128 bf16
    unsigned short* h2s = xa + (size_t)N * 128;           // (N+1)*64 bf16

    // 1) setup (bcnt zero + weight packs + h2s sentinel) -> CSR build
    setup_kernel<<<13, 256, 0, stream>>>(W1, W2, w1p, w2p,
                                         (unsigned*)(h2s + (size_t)N * 64), bcnt);
    bin_kernel<<<(E + BIN_TILE - 1) / BIN_TILE, 256, 0, stream>>>(row, col, bcnt, tmp, E, NB);
    bucket_kernel<<<NB, 256, 0, stream>>>(tmp, bcnt, cnt, offs, dis, csr, N, NB);

    // 2) pre-scaled bf16 features
    {
        long total8 = (long)(N + 1) * 16;
        scale_cvt_kernel<<<(int)((total8 + 255) / 256), 256, 0, stream>>>(x, dis, xbs, N);
    }

    // 3) xa = Dc * (sum + self) on pre-scaled rows
    gather1_kernel<<<(N + 3) / 4, 256, 0, stream>>>(xbs, offs, cnt, csr, dis, xa, N);

    // 4) h2s = dis .* (relu(xa@W1+b1) @ W2)   (fused, a1 only in LDS)
    mlp_kernel<<<(N + 63) / 64, 256, 0, stream>>>(xa, w1p, w2p, b1, dis, h2s, N);

    // 5) out = log_softmax(dc*(sum + self) + b2)
    gather2_kernel<<<(N + 3) / 4, 256, 0, stream>>>(h2s, offs, cnt, csr, dis, b2, out, N);
}

// Round 14
// 175.328 us; speedup vs baseline: 1.1145x; 1.0081x over previous
//
#include <hip/hip_runtime.h>
#include <hip/hip_bf16.h>
#include <math.h>

typedef unsigned short u16x8 __attribute__((ext_vector_type(8)));
typedef short s16x8 __attribute__((ext_vector_type(8)));
typedef float f32x4 __attribute__((ext_vector_type(4)));

#define BIN_TILE 4096
#define BCAP 8192  // per-bucket capacity in tmp; mean fill 4096, sigma ~64

__device__ __forceinline__ float bf2f(unsigned int u) {
    union { unsigned int i; float f; } x;
    x.i = u << 16;
    return x.f;
}
__device__ __forceinline__ unsigned short f2bf(float f) {
    __hip_bfloat16 h = __float2bfloat16(f);
    return *reinterpret_cast<unsigned short*>(&h);
}

// ---------------- setup: zero bcnt + W packs (MFMA B-frag order) + sentinels ----------------
__global__ void setup_kernel(const float* __restrict__ W1, const float* __restrict__ W2,
                             unsigned short* __restrict__ w1p, unsigned short* __restrict__ w2p,
                             unsigned* __restrict__ h2z, unsigned* __restrict__ xz,
                             int* __restrict__ bcnt) {
    int bid = blockIdx.x, tid = threadIdx.x;
    if (bid < 8) {  // w1 pack: 2048 threads
        int t = bid * 256 + tid;
        int lane = t & 63, fc = t >> 6;
        int ct = fc >> 2, kc = fc & 3;
        int n = ct * 16 + (lane & 15);
        int k0 = kc * 32 + (lane >> 4) * 8;
        u16x8 o;
#pragma unroll
        for (int j = 0; j < 8; j++) o[j] = f2bf(W1[(size_t)(k0 + j) * 128 + n]);
        ((u16x8*)w1p)[t] = o;
    } else if (bid < 11) {  // w2 pack: 768 threads
        int t = (bid - 8) * 256 + tid;
        int lane = t & 63, fc = t >> 6;
        int ct = fc >> 2, kc = fc & 3;
        int n = ct * 16 + (lane & 15);
        int k0 = kc * 32 + (lane >> 4) * 8;
        u16x8 o;
#pragma unroll
        for (int j = 0; j < 8; j++) o[j] = (n < 40) ? f2bf(W2[(size_t)(k0 + j) * 40 + n]) : (unsigned short)0;
        ((u16x8*)w2p)[t] = o;
    } else if (bid == 11) {  // zero sentinels: h2s row N (32 u32) + xbs row N (64 u32)
        if (tid < 32) h2z[tid] = 0;
        else if (tid < 96) xz[tid - 32] = 0;
    } else {  // zero bcnt
        bcnt[tid] = 0;
        bcnt[tid + 256] = 0;
    }
}

// ---------------- single-pass bin: LDS hist -> reserve in fixed-cap bucket -> scatter ----------------
// tmp entry = row | (col&255)<<20, at tmp[(col>>8)*BCAP + slot]
__global__ void bin_kernel(const int* __restrict__ row, const int* __restrict__ col,
                           int* __restrict__ bcnt, unsigned* __restrict__ tmp, int E, int NB) {
    __shared__ unsigned hist[512];
    int tid = threadIdx.x;
    int base = blockIdx.x * BIN_TILE;
    int cv[BIN_TILE / 256];  // cache col values across the two passes
    for (int i = tid; i < NB; i += 256) hist[i] = 0;
    __syncthreads();
#pragma unroll
    for (int i = 0; i < BIN_TILE / 256; i++) {
        int e = base + tid + i * 256;
        cv[i] = (e < E) ? col[e] : -1;
        if (cv[i] >= 0) atomicAdd(&hist[cv[i] >> 8], 1u);
    }
    __syncthreads();
    for (int i = tid; i < NB; i += 256) {
        unsigned h = hist[i];
        hist[i] = h ? (unsigned)atomicAdd(&bcnt[i], (int)h) : 0u;  // local cursor base
    }
    __syncthreads();
#pragma unroll
    for (int i = 0; i < BIN_TILE / 256; i++) {
        int e = base + tid + i * 256;
        if (cv[i] >= 0) {
            int c = cv[i], r = row[e];
            unsigned p = atomicAdd(&hist[c >> 8], 1u);
            tmp[(size_t)(c >> 8) * BCAP + p] = (unsigned)r | ((unsigned)(c & 255) << 20);
        }
    }
}

// ---------------- per bucket: prefix + cnt/offs/dis + fine scatter + x->bf16 convert ----------------
__global__ void bucket_kernel(const unsigned* __restrict__ tmp, const int* __restrict__ bcnt,
                              int* __restrict__ cnt, int* __restrict__ offs,
                              float* __restrict__ dis, int* __restrict__ csr,
                              const float* __restrict__ x, unsigned short* __restrict__ xbs,
                              int N, int NB) {
    __shared__ int cntS[256], curS[256], sA[256], sB[256];
    __shared__ float disS[256];
    int b = blockIdx.x;
    int tid = threadIdx.x;
    size_t tbase = (size_t)b * BCAP;

    // start = sum_{i<b} bcnt[i]  (block reduce; bcnt is tiny and L2-hot)
    cntS[tid] = 0;
    int partial = 0;
    if (tid < b) partial += bcnt[tid];
    if (tid + 256 < b) partial += bcnt[tid + 256];
    sA[tid] = partial;
    __syncthreads();
    for (int s = 128; s > 0; s >>= 1) {
        if (tid < s) sA[tid] += sA[tid + s];
        __syncthreads();
    }
    int start = sA[0];
    int ecnt = bcnt[b];

    // per-node degree histogram (LDS)
    for (int i = tid; i < ecnt; i += 256)
        atomicAdd(&cntS[(tmp[tbase + i] >> 20) & 255], 1);
    __syncthreads();
    int myCnt = cntS[tid];
    sA[tid] = myCnt;
    __syncthreads();
    int* src = sA;
    int* dst = sB;
    for (int off = 1; off < 256; off <<= 1) {
        dst[tid] = src[tid] + ((tid >= off) ? src[tid - off] : 0);
        __syncthreads();
        int* t = src; src = dst; dst = t;
    }
    int excl = src[tid] - myCnt;
    int node = (b << 8) + tid;
    float d = rsqrtf((float)myCnt + 1.0f);
    if (node < N) {
        cnt[node] = myCnt;
        offs[node] = start + excl;
        dis[node] = d;
    }
    curS[tid] = excl;
    disS[tid] = d;
    __syncthreads();

    // fine scatter into csr
    for (int i = tid; i < ecnt; i += 256) {
        unsigned u = tmp[tbase + i];
        int cl = (u >> 20) & 255;
        int p = atomicAdd(&curS[cl], 1);
        csr[start + p] = (int)(u & 0xFFFFFu);
    }

    // x -> bf16 pre-scaled conversion for this bucket's 256 rows
    int rbase = b << 8;
    const float4* X4 = (const float4*)x;
    for (int cidx = tid; cidx < 4096; cidx += 256) {
        int rl = cidx >> 4;           // local row 0..255
        int ch = cidx & 15;           // chunk of 8 elems
        int rowg = rbase + rl;
        if (rowg >= N) continue;
        float dd = disS[rl];
        long base8 = (long)rowg * 16 + ch;
        float4 a = X4[2 * base8];
        float4 bb = X4[2 * base8 + 1];
        u16x8 o;
        o[0] = f2bf(dd * a.x); o[1] = f2bf(dd * a.y); o[2] = f2bf(dd * a.z); o[3] = f2bf(dd * a.w);
        o[4] = f2bf(dd * bb.x); o[5] = f2bf(dd * bb.y); o[6] = f2bf(dd * bb.z); o[7] = f2bf(dd * bb.w);
        ((u16x8*)xbs)[base8] = o;
    }
}

// ---------------- gather1: xa[c] = dc * ( sum_s xbs[s] + xbs[c] ), 16 edges in flight ----------------
__global__ void gather1_kernel(const unsigned short* __restrict__ xbs, const int* __restrict__ offs,
                               const int* __restrict__ cnt, const int* __restrict__ csr,
                               const float* __restrict__ dis, unsigned short* __restrict__ xa, int N) {
    int node = blockIdx.x * 4 + (threadIdx.x >> 6);
    int lane = threadIdx.x & 63;
    if (node >= N) return;
    int off = offs[node], dg = cnt[node];
    int g = lane >> 4, c = lane & 15;
    const u16x8* XB = (const u16x8*)xbs;
    float acc[8] = {};
    int s0 = (g      < dg) ? csr[off + g]      : N;
    int s1 = (g + 4  < dg) ? csr[off + g + 4]  : N;
    int s2 = (g + 8  < dg) ? csr[off + g + 8]  : N;
    int s3 = (g + 12 < dg) ? csr[off + g + 12] : N;
    for (int j = 0; j < dg; j += 16) {
        int jb = j + 16;
        int t0 = (jb + g      < dg) ? csr[off + jb + g]      : N;
        int t1 = (jb + g + 4  < dg) ? csr[off + jb + g + 4]  : N;
        int t2 = (jb + g + 8  < dg) ? csr[off + jb + g + 8]  : N;
        int t3 = (jb + g + 12 < dg) ? csr[off + jb + g + 12] : N;
        u16x8 v0 = XB[(size_t)s0 * 16 + c];
        u16x8 v1 = XB[(size_t)s1 * 16 + c];
        u16x8 v2 = XB[(size_t)s2 * 16 + c];
        u16x8 v3 = XB[(size_t)s3 * 16 + c];
#pragma unroll
        for (int k = 0; k < 8; k++)
            acc[k] += (bf2f(v0[k]) + bf2f(v1[k])) + (bf2f(v2[k]) + bf2f(v3[k]));
        s0 = t0; s1 = t1; s2 = t2; s3 = t3;
    }
#pragma unroll
    for (int k = 0; k < 8; k++) {
        acc[k] += __shfl_xor(acc[k], 16);
        acc[k] += __shfl_xor(acc[k], 32);
    }
    float dc = dis[node];
    u16x8 xv = XB[(size_t)node * 16 + c];
    if (lane < 16) {
        u16x8 o;
#pragma unroll
        for (int k = 0; k < 8; k++) o[k] = f2bf(dc * (acc[k] + bf2f(xv[k])));
        ((u16x8*)xa)[(size_t)node * 16 + c] = o;
    }
}

// ---------------- fused MLP (MFMA): h2s = dis .* relu(xa@W1+b1) @ W2 ----------------
__global__ __launch_bounds__(256) void mlp_kernel(const unsigned short* __restrict__ xa,
                                                  const unsigned short* __restrict__ w1p,
                                                  const unsigned short* __restrict__ w2p,
                                                  const float* __restrict__ b1,
                                                  const float* __restrict__ dis,
                                                  unsigned short* __restrict__ h2s, int N) {
    __shared__ unsigned short a1s[64][136];
    int wv = threadIdx.x >> 6;
    int l = threadIdx.x & 63;
    int row16 = l & 15, kg = l >> 4;
    int n0 = blockIdx.x * 64;
    int rbase = n0 + wv * 16;

    f32x4 acc[8];
#pragma unroll
    for (int ct = 0; ct < 8; ct++) acc[ct] = (f32x4)0.f;
    int r = rbase + row16;
    int rc = (r < N) ? r : (N - 1);
#pragma unroll
    for (int kc = 0; kc < 4; kc++) {
        s16x8 af = *(const s16x8*)(xa + (size_t)rc * 128 + kc * 32 + kg * 8);
#pragma unroll
        for (int ct = 0; ct < 8; ct++) {
            s16x8 bf = *(const s16x8*)(w1p + (size_t)((ct * 4 + kc) * 64 + l) * 8);
            acc[ct] = __builtin_amdgcn_mfma_f32_16x16x32_bf16(af, bf, acc[ct], 0, 0, 0);
        }
    }
#pragma unroll
    for (int ct = 0; ct < 8; ct++) {
        float bb = b1[ct * 16 + row16];
#pragma unroll
        for (int v = 0; v < 4; v++)
            a1s[wv * 16 + kg * 4 + v][ct * 16 + row16] = f2bf(fmaxf(acc[ct][v] + bb, 0.f));
    }
    __syncthreads();

    f32x4 acc2[3];
#pragma unroll
    for (int ct = 0; ct < 3; ct++) acc2[ct] = (f32x4)0.f;
#pragma unroll
    for (int kc = 0; kc < 4; kc++) {
        s16x8 af = *(const s16x8*)&a1s[wv * 16 + row16][kc * 32 + kg * 8];
#pragma unroll
        for (int ct = 0; ct < 3; ct++) {
            s16x8 bf = *(const s16x8*)(w2p + (size_t)((ct * 4 + kc) * 64 + l) * 8);
            acc2[ct] = __builtin_amdgcn_mfma_f32_16x16x32_bf16(af, bf, acc2[ct], 0, 0, 0);
        }
    }
#pragma unroll
    for (int v = 0; v < 4; v++) {
        int rr = rbase + kg * 4 + v;
        if (rr < N) {
            float d = dis[rr];
#pragma unroll
            for (int ct = 0; ct < 3; ct++)
                h2s[(size_t)rr * 64 + ct * 16 + row16] = f2bf(d * acc2[ct][v]);
        }
    }
}

// ---------------- gather2: log_softmax(dc*(sum_s h2s[s] + h2s[node]) + b2) ----------------
// 6 groups x 10 lanes (ushort4 = 4 cols/lane), 4 slots -> 24 edges in flight
__global__ void gather2_kernel(const unsigned short* __restrict__ h2s, const int* __restrict__ offs,
                               const int* __restrict__ cnt, const int* __restrict__ csr,
                               const float* __restrict__ dis, const float* __restrict__ b2,
                               float* __restrict__ out, int N) {
    int node = blockIdx.x * 4 + (threadIdx.x >> 6);
    int lane = threadIdx.x & 63;
    if (node >= N) return;
    int off = offs[node], dg = cnt[node];
    int c = lane % 10;            // ushort4 index within row (cols 4c..4c+3)
    int g = lane / 10;
    if (g > 5) g = 5;             // lanes 60-63 duplicate group 5 (harmless)
    const ushort4* H4 = (const ushort4*)h2s;  // 16 ushort4 per 64-col row
    float a0 = 0.f, a1 = 0.f, a2 = 0.f, a3 = 0.f;
    int s0 = (g      < dg) ? csr[off + g]      : N;
    int s1 = (g + 6  < dg) ? csr[off + g + 6]  : N;
    int s2 = (g + 12 < dg) ? csr[off + g + 12] : N;
    int s3 = (g + 18 < dg) ? csr[off + g + 18] : N;
    for (int j = 0; j < dg; j += 24) {
        int jb = j + 24;
        int t0 = (jb + g      < dg) ? csr[off + jb + g]      : N;
        int t1 = (jb + g + 6  < dg) ? csr[off + jb + g + 6]  : N;
        int t2 = (jb + g + 12 < dg) ? csr[off + jb + g + 12] : N;
        int t3 = (jb + g + 18 < dg) ? csr[off + jb + g + 18] : N;
        ushort4 u0 = H4[(size_t)s0 * 16 + c];
        ushort4 u1 = H4[(size_t)s1 * 16 + c];
        ushort4 u2 = H4[(size_t)s2 * 16 + c];
        ushort4 u3 = H4[(size_t)s3 * 16 + c];
        a0 += (bf2f(u0.x) + bf2f(u1.x)) + (bf2f(u2.x) + bf2f(u3.x));
        a1 += (bf2f(u0.y) + bf2f(u1.y)) + (bf2f(u2.y) + bf2f(u3.y));
        a2 += (bf2f(u0.z) + bf2f(u1.z)) + (bf2f(u2.z) + bf2f(u3.z));
        a3 += (bf2f(u0.w) + bf2f(u1.w)) + (bf2f(u2.w) + bf2f(u3.w));
        s0 = t0; s1 = t1; s2 = t2; s3 = t3;
    }
    // fold 6 groups -> lanes 0-9.  step1: lanes 0-29 += lanes 30-59 (g+3)
    float t;
    t = __shfl(a0, lane + 30); a0 += t;
    t = __shfl(a1, lane + 30); a1 += t;
    t = __shfl(a2, lane + 30); a2 += t;
    t = __shfl(a3, lane + 30); a3 += t;
    // step2: lanes 0-9 += lanes 10-19 and 20-29
    float p, q;
    p = __shfl(a0, lane + 10); q = __shfl(a0, lane + 20); a0 += p + q;
    p = __shfl(a1, lane + 10); q = __shfl(a1, lane + 20); a1 += p + q;
    p = __shfl(a2, lane + 10); q = __shfl(a2, lane + 20); a2 += p + q;
    p = __shfl(a3, lane + 10); q = __shfl(a3, lane + 20); a3 += p + q;

    bool act = lane < 10;
    float dc = dis[node];
    ushort4 uv = H4[(size_t)node * 16 + c];
    float4 bb = ((const float4*)b2)[c];  // cols 4c..4c+3
    float v0 = -INFINITY, v1 = -INFINITY, v2 = -INFINITY, v3 = -INFINITY;
    if (act) {
        v0 = dc * (a0 + bf2f(uv.x)) + bb.x;
        v1 = dc * (a1 + bf2f(uv.y)) + bb.y;
        v2 = dc * (a2 + bf2f(uv.z)) + bb.z;
        v3 = dc * (a3 + bf2f(uv.w)) + bb.w;
    }
    float m = fmaxf(fmaxf(v0, v1), fmaxf(v2, v3));
#pragma unroll
    for (int o = 32; o > 0; o >>= 1) m = fmaxf(m, __shfl_xor(m, o));
    float ex = act ? (__expf(v0 - m) + __expf(v1 - m) + __expf(v2 - m) + __expf(v3 - m)) : 0.f;
#pragma unroll
    for (int o = 32; o > 0; o >>= 1) ex += __shfl_xor(ex, o);
    float ls = __logf(ex);  // values live only on lanes 0-9 -> single-counted
    if (act) {
        float4 o4 = make_float4(v0 - m - ls, v1 - m - ls, v2 - m - ls, v3 - m - ls);
        ((float4*)(out + (size_t)node * 40))[c] = o4;
    }
}

extern "C" void kernel_launch(void* const* d_in, const int* in_sizes, int n_in,
                              void* d_out, int out_size, void* d_ws, size_t ws_size,
                              hipStream_t stream) {
    const float* x  = (const float*)d_in[0];
    const int*   ei = (const int*)d_in[1];
    const float* W1 = (const float*)d_in[2];
    const float* b1 = (const float*)d_in[3];
    const float* W2 = (const float*)d_in[4];
    const float* b2 = (const float*)d_in[5];
    float* out = (float*)d_out;

    const int N = in_sizes[0] / 128;
    const int E = in_sizes[1] / 2;
    const int* row = ei;
    const int* col = ei + E;

    const int Npad = (N + 511) & ~511;
    const int Epad = (E + 511) & ~511;
    const int NB = (N + 255) >> 8;  // coarse buckets (col>>8); <=512

    int* cnt      = (int*)d_ws;           // Npad
    int* offs     = cnt + Npad;           // Npad
    int* bcnt     = offs + Npad;          // 512 (pad 1024)
    int* csr      = bcnt + 1024;          // Epad
    unsigned* tmp = (unsigned*)(csr + Epad);              // NB*BCAP (<= 512*8192 = 16MB)
    float* dis    = (float*)(tmp + (size_t)NB * BCAP);    // Npad
    unsigned short* w1p = (unsigned short*)(dis + Npad);  // 16384 ush
    unsigned short* w2p = w1p + 16384;                    // 6144 ush (pad 8192)
    unsigned short* xbs = w2p + 8192;                     // (N+1)*128 bf16
    unsigned short* xa  = xbs + (size_t)(N + 1) * 128;    // N*128 bf16
    unsigned short* h2s = xa + (size_t)N * 128;           // (N+1)*64 bf16

    // 1) setup (bcnt zero + weight packs + sentinels) -> CSR build (+ fused x->bf16 cvt)
    setup_kernel<<<13, 256, 0, stream>>>(W1, W2, w1p, w2p,
                                         (unsigned*)(h2s + (size_t)N * 64),
                                         (unsigned*)(xbs + (size_t)N * 128), bcnt);
    bin_kernel<<<(E + BIN_TILE - 1) / BIN_TILE, 256, 0, stream>>>(row, col, bcnt, tmp, E, NB);
    bucket_kernel<<<NB, 256, 0, stream>>>(tmp, bcnt, cnt, offs, dis, csr, x, xbs, N, NB);

    // 2) xa = Dc * (sum + self) on pre-scaled rows
    gather1_kernel<<<(N + 3) / 4, 256, 0, stream>>>(xbs, offs, cnt, csr, dis, xa, N);

    // 3) h2s = dis .* (relu(xa@W1+b1) @ W2)   (fused, a1 only in LDS)
    mlp_kernel<<<(N + 63) / 64, 256, 0, stream>>>(xa, w1p, w2p, b1, dis, h2s, N);

    // 4) out = log_softmax(dc*(sum + self) + b2)
    gather2_kernel<<<(N + 3) / 4, 256, 0, stream>>>(h2s, offs, cnt, csr, dis, b2, out, N);
}